// Round 2
// baseline (155.612 us; speedup 1.0000x reference)
//
#include <hip/hip_runtime.h>
#include <math.h>

#define N_G 1024
#define HW 128
#define NPIX (HW * HW)

// d_out offsets (flat float output, reference return order)
#define OFF_COLOR  0                        // (3,128,128)
#define OFF_LANG   49152                    // (8,128,128)
#define OFF_RADII  180224                   // (1024,)
#define OFF_RADIIL 181248                   // (1024,)
#define OFF_DEPTH  182272                   // (1,128,128)
#define OFF_OPAC   198656                   // (1,128,128)
#define OFF_OPACL  215040                   // (1,128,128)
#define OFF_NT     231424                   // (1024,)
#define OFF_NTL    232448                   // (1024,)

// ws layout (floats):
//  P[r]: AoS records, 20 floats (80B) per gaussian, depth-sorted:
//    [0 px, 1 py, 2 ca, 3 cb | 4 cc, 5 op, 6 pm, 7 tz | 8..15 feat | 16 oi, 17..19 pad]
//  SCAN[r]: float4 {px, py, bx, by} per sorted gaussian (bbox half-extents +2px margin)
#define WS_P(r)     ((r) * 20 * N_G)
#define WS_SCAN(r)  (40 * N_G + (r) * 4 * N_G)
// total: 48 * N_G floats = 192 KiB of d_ws

// ---------------------------------------------------------------------------
// Preprocess + stable depth sort (one block per render pass)
// ---------------------------------------------------------------------------
__global__ __launch_bounds__(1024) void k_pre_sort(
    const float* __restrict__ means3D,
    const float* __restrict__ colors, const float* __restrict__ lang,
    const float* __restrict__ opac, const float* __restrict__ opacl,
    const float* __restrict__ scales, const float* __restrict__ scalesl,
    const float* __restrict__ rots, const float* __restrict__ rotsl,
    const float* __restrict__ V, const float* __restrict__ P,
    float* __restrict__ ws, float* __restrict__ out)
{
    int r = blockIdx.x;          // 0 = color pass, 1 = language pass
    int n = threadIdx.x;         // gaussian id
    const float* sc = r ? scalesl : scales;
    const float* qt = r ? rotsl : rots;
    const float* op = r ? opacl : opac;
    const float* ft = r ? lang : colors;
    int F = r ? 8 : 3;

    float m0 = means3D[n * 3 + 0], m1 = means3D[n * 3 + 1], m2 = means3D[n * 3 + 2];
    // t = [m,1] @ V  (row-vector times row-major 4x4)
    float t0 = m0 * V[0] + m1 * V[4] + m2 * V[8]  + V[12];
    float t1 = m0 * V[1] + m1 * V[5] + m2 * V[9]  + V[13];
    float tz = m0 * V[2] + m1 * V[6] + m2 * V[10] + V[14];
    // ph = [m,1] @ P
    float ph0 = m0 * P[0] + m1 * P[4] + m2 * P[8]  + P[12];
    float ph1 = m0 * P[1] + m1 * P[5] + m2 * P[9]  + P[13];
    float ph3 = m0 * P[3] + m1 * P[7] + m2 * P[11] + P[15];
    float pw = 1.0f / (ph3 + 1e-7f);
    float px = ((ph0 * pw + 1.0f) * (float)HW - 1.0f) * 0.5f;
    float py = ((ph1 * pw + 1.0f) * (float)HW - 1.0f) * 0.5f;

    // quaternion -> rotation
    float q0 = qt[n * 4 + 0], q1 = qt[n * 4 + 1], q2 = qt[n * 4 + 2], q3 = qt[n * 4 + 3];
    float qinv = 1.0f / sqrtf(q0 * q0 + q1 * q1 + q2 * q2 + q3 * q3);
    q0 *= qinv; q1 *= qinv; q2 *= qinv; q3 *= qinv;
    float rr = q0, x = q1, y = q2, z = q3;
    float R0 = 1.0f - 2.0f * (y * y + z * z), R1 = 2.0f * (x * y - rr * z), R2 = 2.0f * (x * z + rr * y);
    float R3 = 2.0f * (x * y + rr * z), R4 = 1.0f - 2.0f * (x * x + z * z), R5 = 2.0f * (y * z - rr * x);
    float R6 = 2.0f * (x * z - rr * y), R7 = 2.0f * (y * z + rr * x), R8 = 1.0f - 2.0f * (x * x + y * y);
    float s0 = sc[n * 3 + 0], s1 = sc[n * 3 + 1], s2 = sc[n * 3 + 2]; // SCALE_MOD = 1
    float M0 = R0 * s0, M1 = R1 * s1, M2 = R2 * s2;
    float M3 = R3 * s0, M4 = R4 * s1, M5 = R5 * s2;
    float M6 = R6 * s0, M7 = R7 * s1, M8 = R8 * s2;
    // cov3d = M M^T (symmetric)
    float c300 = M0 * M0 + M1 * M1 + M2 * M2;
    float c301 = M0 * M3 + M1 * M4 + M2 * M5;
    float c302 = M0 * M6 + M1 * M7 + M2 * M8;
    float c311 = M3 * M3 + M4 * M4 + M5 * M5;
    float c312 = M3 * M6 + M4 * M7 + M5 * M8;
    float c322 = M6 * M6 + M7 * M7 + M8 * M8;

    const float fx = (float)HW / (2.0f * 0.7f);
    const float fy = fx;
    const float limx = 1.3f * 0.7f, limy = 1.3f * 0.7f;
    float txz = fminf(fmaxf(t0 / tz, -limx), limx) * tz;
    float tyz = fminf(fmaxf(t1 / tz, -limy), limy) * tz;
    float J00 = fx / tz, J02 = -fx * txz / (tz * tz);
    float J11 = fy / tz, J12 = -fy * tyz / (tz * tz);
    // T2 = J @ Wr, Wr[i][j] = V[j*4+i]
    float a0 = J00 * V[0] + J02 * V[2];
    float a1 = J00 * V[4] + J02 * V[6];
    float a2 = J00 * V[8] + J02 * V[10];
    float b0 = J11 * V[1] + J12 * V[2];
    float b1 = J11 * V[5] + J12 * V[6];
    float b2 = J11 * V[9] + J12 * V[10];
    // cov2 = T2 cov3d T2^T + 0.3 I
    float u0 = c300 * a0 + c301 * a1 + c302 * a2;
    float u1 = c301 * a0 + c311 * a1 + c312 * a2;
    float u2 = c302 * a0 + c312 * a1 + c322 * a2;
    float v0 = c300 * b0 + c301 * b1 + c302 * b2;
    float v1 = c301 * b0 + c311 * b1 + c312 * b2;
    float v2 = c302 * b0 + c312 * b1 + c322 * b2;
    float c00 = a0 * u0 + a1 * u1 + a2 * u2 + 0.3f;
    float c01 = b0 * u0 + b1 * u1 + b2 * u2;
    float c11 = b0 * v0 + b1 * v1 + b2 * v2 + 0.3f;

    float det = c00 * c11 - c01 * c01;
    float invdet = 1.0f / (det + 1e-12f);
    float ca = c11 * invdet, cb = -c01 * invdet, cc = c00 * invdet;
    float mid = 0.5f * (c00 + c11);
    float lam1 = mid + sqrtf(fmaxf(0.1f, mid * mid - det));
    bool valid = (tz > 0.2f) && (det > 0.0f);
    float radf = valid ? ceilf(3.0f * sqrtf(lam1)) : 0.0f;
    float o = op[n];
    float opEff = valid ? o : 0.0f;           // folds 'valid' into alpha == 0
    float pmin, bx, by;
    if (opEff > 0.0f) {
        pmin = -logf(255.0f * opEff);         // alpha >= 1/255  <=>  power >= pmin
        float Q = -2.0f * pmin;               // support: q(d) <= Q (exact ellipse)
        if (Q > 0.0f) {
            bx = sqrtf(Q * c00) + 2.0f;       // exact axis extent sqrt(Q*cov2_00) + 2px margin
            by = sqrtf(Q * c11) + 2.0f;
        } else { bx = -1e30f; by = -1e30f; }  // op <= 1/255: empty support
    } else {
        pmin = __builtin_inff();
        bx = -1e30f; by = -1e30f;             // never hits any tile
    }

    // stable ascending rank sort, key = valid ? tz : inf (matches jnp.argsort)
    __shared__ float keys[N_G];
    float key = valid ? tz : __builtin_inff();
    keys[n] = key;
    __syncthreads();
    int rank = 0;
    for (int j = 0; j < N_G; ++j) {
        float kj = keys[j];
        rank += (kj < key || (kj == key && j < n)) ? 1 : 0;
    }

    float f8[8];
    #pragma unroll
    for (int f = 0; f < 8; ++f) f8[f] = (f < F) ? ft[n * F + f] : 0.0f;

    float* bp = ws + WS_P(r) + rank * 20;
    ((float4*)bp)[0] = make_float4(px, py, ca, cb);
    ((float4*)bp)[1] = make_float4(cc, opEff, pmin, tz);
    ((float4*)bp)[2] = make_float4(f8[0], f8[1], f8[2], f8[3]);
    ((float4*)bp)[3] = make_float4(f8[4], f8[5], f8[6], f8[7]);
    ((float4*)bp)[4] = make_float4((float)n, 0.0f, 0.0f, 0.0f);
    ((float4*)(ws + WS_SCAN(r)))[rank] = make_float4(px, py, bx, by);

    out[(r ? OFF_RADIIL : OFF_RADII) + n] = radf;
    out[(r ? OFF_NTL : OFF_NT) + n] = 0.0f;   // zero-init for render atomics
}

// ---------------------------------------------------------------------------
// Per-tile render: scan+cull (exact support bbox) -> ordered list -> blend
// one 64-thread block per 8x8 pixel tile; grid (256 tiles, 2 passes)
// ---------------------------------------------------------------------------
__global__ __launch_bounds__(64) void k_render(
    const float* __restrict__ ws, const float* __restrict__ bg,
    float* __restrict__ out)
{
    int r = (int)blockIdx.y;
    int tile = (int)blockIdx.x;
    int t = (int)threadIdx.x;
    int tx = t & 7, ty = t >> 3;
    int x0 = (tile & 15) * 8, y0 = (tile >> 4) * 8;
    int px_i = x0 + tx, py_i = y0 + ty;
    float fpx = (float)px_i, fpy = (float)py_i;
    float xmin = (float)x0, xmax = (float)(x0 + 7);
    float ymin = (float)y0, ymax = (float)(y0 + 7);

    __shared__ int s_list[N_G];
    __shared__ __align__(16) float s_a[64 * 20];   // staged AoS records

    // ---- phase 1: cull. all 16 chunk loads issued up-front (single latency) ----
    const float4* sc4 = (const float4*)(ws + WS_SCAN(r));
    float4 gv[16];
    #pragma unroll
    for (int c = 0; c < 16; ++c) gv[c] = sc4[c * 64 + t];

    int cnt = 0;
    #pragma unroll
    for (int c = 0; c < 16; ++c) {
        float gpx = gv[c].x, gpy = gv[c].y, gbx = gv[c].z, gby = gv[c].w;
        bool hit = (gpx - gbx <= xmax) && (gpx + gbx >= xmin) &&
                   (gpy - gby <= ymax) && (gpy + gby >= ymin);
        unsigned long long m = __ballot(hit);
        if (hit) {
            int off = __popcll(m & ((1ull << t) - 1ull));
            s_list[cnt + off] = c * 64 + t;         // sorted order preserved
        }
        cnt += __popcll(m);
    }
    __syncthreads();

    // ---- phase 2: ordered front-to-back blend over the list ----
    float T = 1.0f;
    float acc[8] = {0, 0, 0, 0, 0, 0, 0, 0};
    float dacc = 0.0f;
    const float ONE255 = 1.0f / 255.0f;

    for (int b = 0; b < cnt; b += 64) {
        int jmax = min(64, cnt - b);
        if (t < jmax) {
            int idx = s_list[b + t];
            const float4* gp = (const float4*)(ws + WS_P(r) + idx * 20);
            float4 v0 = gp[0], v1 = gp[1], v2 = gp[2], v3 = gp[3], v4 = gp[4];
            float4* dp = (float4*)(s_a + t * 20);
            dp[0] = v0; dp[1] = v1; dp[2] = v2; dp[3] = v3; dp[4] = v4;
        }
        __syncthreads();

        for (int j = 0; j < jmax; ++j) {
            const float4* aj = (const float4*)(s_a + j * 20);
            float4 A = aj[0];                        // px,py,ca,cb
            float4 B = aj[1];                        // cc,op,pm,tz
            float dx = A.x - fpx, dy = A.y - fpy;
            float power = -0.5f * (A.z * dx * dx + B.x * dy * dy) - A.w * dx * dy;
            float alpha = 0.0f;
            // conservative precheck gates expf; final decision is exact reference math
            if (power <= 0.0f && power >= B.z - 1e-3f) {
                alpha = fminf(0.99f, B.y * expf(power));
                if (alpha < ONE255) alpha = 0.0f;
            }
            unsigned long long m = __ballot(alpha > 0.0f);
            if (m) {
                float4 C = aj[2];                    // feat 0..3
                float w = alpha * T;
                if (r == 0) {
                    acc[0] += w * C.x;
                    acc[1] += w * C.y;
                    acc[2] += w * C.z;
                    dacc   += w * B.w;
                } else {
                    float4 D = aj[3];                // feat 4..7
                    acc[0] += w * C.x; acc[1] += w * C.y;
                    acc[2] += w * C.z; acc[3] += w * C.w;
                    acc[4] += w * D.x; acc[5] += w * D.y;
                    acc[6] += w * D.z; acc[7] += w * D.w;
                }
                T *= (1.0f - alpha);
                if (t == 0) {
                    int orig = (int)aj[4].x;
                    atomicAdd(&out[(r ? OFF_NTL : OFF_NT) + orig], (float)__popcll(m));
                }
            }
        }
        __syncthreads();
    }

    int p = py_i * HW + px_i;
    if (r == 0) {
        out[OFF_COLOR + 0 * NPIX + p] = acc[0] + T * bg[0];
        out[OFF_COLOR + 1 * NPIX + p] = acc[1] + T * bg[1];
        out[OFF_COLOR + 2 * NPIX + p] = acc[2] + T * bg[2];
        out[OFF_DEPTH + p] = dacc;
        out[OFF_OPAC + p] = 1.0f - T;
    } else {
        #pragma unroll
        for (int f = 0; f < 8; ++f)
            out[OFF_LANG + f * NPIX + p] = acc[f];
        out[OFF_OPACL + p] = 1.0f - T;
    }
}

extern "C" void kernel_launch(void* const* d_in, const int* in_sizes, int n_in,
                              void* d_out, int out_size, void* d_ws, size_t ws_size,
                              hipStream_t stream)
{
    const float* means3D = (const float*)d_in[0];
    // d_in[1] = means2D (unused)
    const float* colors  = (const float*)d_in[2];
    const float* lang    = (const float*)d_in[3];
    const float* opac    = (const float*)d_in[4];
    const float* opacl   = (const float*)d_in[5];
    const float* scales  = (const float*)d_in[6];
    const float* scalesl = (const float*)d_in[7];
    const float* rots    = (const float*)d_in[8];
    const float* rotsl   = (const float*)d_in[9];
    const float* V       = (const float*)d_in[10];
    const float* P       = (const float*)d_in[11];
    const float* bg      = (const float*)d_in[12];
    // d_in[13] = campos (unused)

    float* out = (float*)d_out;
    float* ws  = (float*)d_ws;

    hipLaunchKernelGGL(k_pre_sort, dim3(2), dim3(1024), 0, stream,
                       means3D, colors, lang, opac, opacl, scales, scalesl,
                       rots, rotsl, V, P, ws, out);
    hipLaunchKernelGGL(k_render, dim3(256, 2), dim3(64), 0, stream,
                       ws, bg, out);
}

// Round 3
// 118.738 us; speedup vs baseline: 1.3105x; 1.3105x over previous
//
#include <hip/hip_runtime.h>
#include <math.h>

#define N_G 1024
#define HW 128
#define NPIX (HW * HW)

// d_out offsets (flat float output, reference return order)
#define OFF_COLOR  0                        // (3,128,128)
#define OFF_LANG   49152                    // (8,128,128)
#define OFF_RADII  180224                   // (1024,)
#define OFF_RADIIL 181248                   // (1024,)
#define OFF_DEPTH  182272                   // (1,128,128)
#define OFF_OPAC   198656                   // (1,128,128)
#define OFF_OPACL  215040                   // (1,128,128)
#define OFF_NT     231424                   // (1024,)
#define OFF_NTL    232448                   // (1024,)

// ws layout (floats), all arrays indexed by ORIGINAL gaussian id (no global sort):
//  REC[r][n]  : 16 floats (4x float4): [px,py,ca,cb][cc,op,pm,tz][f0..3][f4..7]
//  SCAN[r][n] : float4 {px,py,bx,by}  (bbox half-extents, exact support + 2px)
//  KEY[r][n]  : u64 = (float_bits(valid?tz:inf) << 32) | n   -- unique, argsort-stable
#define WS_REC(r)   ((r) * 16 * N_G)
#define WS_SCAN(r)  (32 * N_G + (r) * 4 * N_G)
#define WS_KEY(r)   (40 * N_G + (r) * 2 * N_G)
// total: 44 * N_G floats = 176 KiB of d_ws

// ---------------------------------------------------------------------------
// Per-gaussian preprocess, fully parallel (2048 independent threads)
// ---------------------------------------------------------------------------
__global__ __launch_bounds__(256) void k_pre(
    const float* __restrict__ means3D,
    const float* __restrict__ colors, const float* __restrict__ lang,
    const float* __restrict__ opac, const float* __restrict__ opacl,
    const float* __restrict__ scales, const float* __restrict__ scalesl,
    const float* __restrict__ rots, const float* __restrict__ rotsl,
    const float* __restrict__ V, const float* __restrict__ P,
    float* __restrict__ ws, float* __restrict__ out)
{
    int idx = blockIdx.x * 256 + threadIdx.x;
    if (idx >= 2 * N_G) return;
    int r = idx >> 10;           // 0 = color pass, 1 = language pass
    int n = idx & (N_G - 1);
    const float* sc = r ? scalesl : scales;
    const float* qt = r ? rotsl : rots;
    const float* op = r ? opacl : opac;
    const float* ft = r ? lang : colors;
    int F = r ? 8 : 3;

    float m0 = means3D[n * 3 + 0], m1 = means3D[n * 3 + 1], m2 = means3D[n * 3 + 2];
    // t = [m,1] @ V  (row-vector times row-major 4x4)
    float t0 = m0 * V[0] + m1 * V[4] + m2 * V[8]  + V[12];
    float t1 = m0 * V[1] + m1 * V[5] + m2 * V[9]  + V[13];
    float tz = m0 * V[2] + m1 * V[6] + m2 * V[10] + V[14];
    // ph = [m,1] @ P
    float ph0 = m0 * P[0] + m1 * P[4] + m2 * P[8]  + P[12];
    float ph1 = m0 * P[1] + m1 * P[5] + m2 * P[9]  + P[13];
    float ph3 = m0 * P[3] + m1 * P[7] + m2 * P[11] + P[15];
    float pw = 1.0f / (ph3 + 1e-7f);
    float px = ((ph0 * pw + 1.0f) * (float)HW - 1.0f) * 0.5f;
    float py = ((ph1 * pw + 1.0f) * (float)HW - 1.0f) * 0.5f;

    // quaternion -> rotation
    float q0 = qt[n * 4 + 0], q1 = qt[n * 4 + 1], q2 = qt[n * 4 + 2], q3 = qt[n * 4 + 3];
    float qinv = 1.0f / sqrtf(q0 * q0 + q1 * q1 + q2 * q2 + q3 * q3);
    q0 *= qinv; q1 *= qinv; q2 *= qinv; q3 *= qinv;
    float rr = q0, x = q1, y = q2, z = q3;
    float R0 = 1.0f - 2.0f * (y * y + z * z), R1 = 2.0f * (x * y - rr * z), R2 = 2.0f * (x * z + rr * y);
    float R3 = 2.0f * (x * y + rr * z), R4 = 1.0f - 2.0f * (x * x + z * z), R5 = 2.0f * (y * z - rr * x);
    float R6 = 2.0f * (x * z - rr * y), R7 = 2.0f * (y * z + rr * x), R8 = 1.0f - 2.0f * (x * x + y * y);
    float s0 = sc[n * 3 + 0], s1 = sc[n * 3 + 1], s2 = sc[n * 3 + 2]; // SCALE_MOD = 1
    float M0 = R0 * s0, M1 = R1 * s1, M2 = R2 * s2;
    float M3 = R3 * s0, M4 = R4 * s1, M5 = R5 * s2;
    float M6 = R6 * s0, M7 = R7 * s1, M8 = R8 * s2;
    // cov3d = M M^T (symmetric)
    float c300 = M0 * M0 + M1 * M1 + M2 * M2;
    float c301 = M0 * M3 + M1 * M4 + M2 * M5;
    float c302 = M0 * M6 + M1 * M7 + M2 * M8;
    float c311 = M3 * M3 + M4 * M4 + M5 * M5;
    float c312 = M3 * M6 + M4 * M7 + M5 * M8;
    float c322 = M6 * M6 + M7 * M7 + M8 * M8;

    const float fx = (float)HW / (2.0f * 0.7f);
    const float fy = fx;
    const float limx = 1.3f * 0.7f, limy = 1.3f * 0.7f;
    float txz = fminf(fmaxf(t0 / tz, -limx), limx) * tz;
    float tyz = fminf(fmaxf(t1 / tz, -limy), limy) * tz;
    float J00 = fx / tz, J02 = -fx * txz / (tz * tz);
    float J11 = fy / tz, J12 = -fy * tyz / (tz * tz);
    // T2 = J @ Wr, Wr[i][j] = V[j*4+i]
    float a0 = J00 * V[0] + J02 * V[2];
    float a1 = J00 * V[4] + J02 * V[6];
    float a2 = J00 * V[8] + J02 * V[10];
    float b0 = J11 * V[1] + J12 * V[2];
    float b1 = J11 * V[5] + J12 * V[6];
    float b2 = J11 * V[9] + J12 * V[10];
    // cov2 = T2 cov3d T2^T + 0.3 I
    float u0 = c300 * a0 + c301 * a1 + c302 * a2;
    float u1 = c301 * a0 + c311 * a1 + c312 * a2;
    float u2 = c302 * a0 + c312 * a1 + c322 * a2;
    float v0 = c300 * b0 + c301 * b1 + c302 * b2;
    float v1 = c301 * b0 + c311 * b1 + c312 * b2;
    float v2 = c302 * b0 + c312 * b1 + c322 * b2;
    float c00 = a0 * u0 + a1 * u1 + a2 * u2 + 0.3f;
    float c01 = b0 * u0 + b1 * u1 + b2 * u2;
    float c11 = b0 * v0 + b1 * v1 + b2 * v2 + 0.3f;

    float det = c00 * c11 - c01 * c01;
    float invdet = 1.0f / (det + 1e-12f);
    float ca = c11 * invdet, cb = -c01 * invdet, cc = c00 * invdet;
    float mid = 0.5f * (c00 + c11);
    float lam1 = mid + sqrtf(fmaxf(0.1f, mid * mid - det));
    bool valid = (tz > 0.2f) && (det > 0.0f);
    float radf = valid ? ceilf(3.0f * sqrtf(lam1)) : 0.0f;
    float o = op[n];
    float opEff = valid ? o : 0.0f;           // folds 'valid' into alpha == 0
    float pmin, bx, by;
    if (opEff > 0.0f) {
        pmin = -logf(255.0f * opEff);         // alpha >= 1/255  <=>  power >= pmin
        float Q = -2.0f * pmin;               // support: q(d) <= Q (exact ellipse)
        if (Q > 0.0f) {
            bx = sqrtf(Q * c00) + 2.0f;       // exact axis extent sqrt(Q*cov2_00) + 2px
            by = sqrtf(Q * c11) + 2.0f;
        } else { bx = -1e30f; by = -1e30f; }  // op <= 1/255: empty support
    } else {
        pmin = __builtin_inff();
        bx = -1e30f; by = -1e30f;             // never hits any tile
    }

    float f8[8];
    #pragma unroll
    for (int f = 0; f < 8; ++f) f8[f] = (f < F) ? ft[n * F + f] : 0.0f;

    float* rec = ws + WS_REC(r) + n * 16;
    ((float4*)rec)[0] = make_float4(px, py, ca, cb);
    ((float4*)rec)[1] = make_float4(cc, opEff, pmin, tz);
    ((float4*)rec)[2] = make_float4(f8[0], f8[1], f8[2], f8[3]);
    ((float4*)rec)[3] = make_float4(f8[4], f8[5], f8[6], f8[7]);
    ((float4*)(ws + WS_SCAN(r)))[n] = make_float4(px, py, bx, by);

    // unique sort key: positive-float bit order == value order; index => stable
    float keyf = valid ? tz : __builtin_inff();
    ((unsigned long long*)(ws + WS_KEY(r)))[n] =
        ((unsigned long long)__float_as_uint(keyf) << 32) | (unsigned)n;

    out[(r ? OFF_RADIIL : OFF_RADII) + n] = radf;
    out[(r ? OFF_NTL : OFF_NT) + n] = 0.0f;   // zero-init for render atomics
}

// ---------------------------------------------------------------------------
// Per-tile render: cull (exact support bbox) -> local depth sort -> blend
// one 64-thread block (1 wave) per 8x8 pixel tile; grid (256 tiles, 2 passes)
// ---------------------------------------------------------------------------
__global__ __launch_bounds__(64) void k_render(
    const float* __restrict__ ws, const float* __restrict__ bg,
    float* __restrict__ out)
{
    int r = (int)blockIdx.y;
    int tile = (int)blockIdx.x;
    int t = (int)threadIdx.x;
    int tx = t & 7, ty = t >> 3;
    int x0 = (tile & 15) * 8, y0 = (tile >> 4) * 8;
    int px_i = x0 + tx, py_i = y0 + ty;
    float fpx = (float)px_i, fpy = (float)py_i;
    float xmin = (float)x0, xmax = (float)(x0 + 7);
    float ymin = (float)y0, ymax = (float)(y0 + 7);

    __shared__ int s_idx[N_G];
    __shared__ unsigned long long s_key[N_G];
    __shared__ int s_ord[N_G];
    __shared__ __align__(16) float s_a[64 * 16];
    __shared__ int s_oi[64];

    // ---- phase 1: cull (all 16 chunk loads in flight -> one latency) ----
    const float4* sc4 = (const float4*)(ws + WS_SCAN(r));
    float4 gv[16];
    #pragma unroll
    for (int c = 0; c < 16; ++c) gv[c] = sc4[c * 64 + t];

    int cnt = 0;
    #pragma unroll
    for (int c = 0; c < 16; ++c) {
        float gpx = gv[c].x, gpy = gv[c].y, gbx = gv[c].z, gby = gv[c].w;
        bool hit = (gpx - gbx <= xmax) && (gpx + gbx >= xmin) &&
                   (gpy - gby <= ymax) && (gpy + gby >= ymin);
        unsigned long long m = __ballot(hit);
        if (hit) {
            int off = __popcll(m & ((1ull << t) - 1ull));
            s_idx[cnt + off] = c * 64 + t;
        }
        cnt += __popcll(m);
    }
    __syncthreads();

    // ---- phase 2: gather keys of hits ----
    const unsigned long long* keyp = (const unsigned long long*)(ws + WS_KEY(r));
    for (int k = t; k < cnt; k += 64) s_key[k] = keyp[s_idx[k]];
    __syncthreads();

    // ---- phase 3: local rank sort (keys are unique) ----
    for (int k = t; k < cnt; k += 64) {
        unsigned long long my = s_key[k];
        int rank = 0;
        for (int j = 0; j < cnt; ++j) rank += (s_key[j] < my) ? 1 : 0;
        s_ord[rank] = s_idx[k];
    }
    __syncthreads();

    // ---- phase 4: ordered front-to-back blend ----
    float T = 1.0f;
    float acc[8] = {0, 0, 0, 0, 0, 0, 0, 0};
    float dacc = 0.0f;
    const float ONE255 = 1.0f / 255.0f;

    for (int b = 0; b < cnt; b += 64) {
        int jmax = min(64, cnt - b);
        if (t < jmax) {
            int gi = s_ord[b + t];
            s_oi[t] = gi;
            const float4* gp = (const float4*)(ws + WS_REC(r) + gi * 16);
            float4 v0 = gp[0], v1 = gp[1], v2 = gp[2], v3 = gp[3];
            float4* dp = (float4*)(s_a + t * 16);
            dp[0] = v0; dp[1] = v1; dp[2] = v2; dp[3] = v3;
        }
        __syncthreads();

        for (int j = 0; j < jmax; ++j) {
            const float4* aj = (const float4*)(s_a + j * 16);
            float4 A = aj[0];                        // px,py,ca,cb
            float4 B = aj[1];                        // cc,op,pm,tz
            float dx = A.x - fpx, dy = A.y - fpy;
            float power = -0.5f * (A.z * dx * dx + B.x * dy * dy) - A.w * dx * dy;
            float alpha = 0.0f;
            // conservative precheck gates expf; final decision is exact reference math
            if (power <= 0.0f && power >= B.z - 1e-3f) {
                alpha = fminf(0.99f, B.y * expf(power));
                if (alpha < ONE255) alpha = 0.0f;
            }
            unsigned long long m = __ballot(alpha > 0.0f);
            if (m) {
                float4 C = aj[2];                    // feat 0..3
                float w = alpha * T;
                if (r == 0) {
                    acc[0] += w * C.x;
                    acc[1] += w * C.y;
                    acc[2] += w * C.z;
                    dacc   += w * B.w;
                } else {
                    float4 D = aj[3];                // feat 4..7
                    acc[0] += w * C.x; acc[1] += w * C.y;
                    acc[2] += w * C.z; acc[3] += w * C.w;
                    acc[4] += w * D.x; acc[5] += w * D.y;
                    acc[6] += w * D.z; acc[7] += w * D.w;
                }
                T *= (1.0f - alpha);
                if (t == 0) {
                    atomicAdd(&out[(r ? OFF_NTL : OFF_NT) + s_oi[j]],
                              (float)__popcll(m));
                }
            }
        }
        __syncthreads();
    }

    int p = py_i * HW + px_i;
    if (r == 0) {
        out[OFF_COLOR + 0 * NPIX + p] = acc[0] + T * bg[0];
        out[OFF_COLOR + 1 * NPIX + p] = acc[1] + T * bg[1];
        out[OFF_COLOR + 2 * NPIX + p] = acc[2] + T * bg[2];
        out[OFF_DEPTH + p] = dacc;
        out[OFF_OPAC + p] = 1.0f - T;
    } else {
        #pragma unroll
        for (int f = 0; f < 8; ++f)
            out[OFF_LANG + f * NPIX + p] = acc[f];
        out[OFF_OPACL + p] = 1.0f - T;
    }
}

extern "C" void kernel_launch(void* const* d_in, const int* in_sizes, int n_in,
                              void* d_out, int out_size, void* d_ws, size_t ws_size,
                              hipStream_t stream)
{
    const float* means3D = (const float*)d_in[0];
    // d_in[1] = means2D (unused)
    const float* colors  = (const float*)d_in[2];
    const float* lang    = (const float*)d_in[3];
    const float* opac    = (const float*)d_in[4];
    const float* opacl   = (const float*)d_in[5];
    const float* scales  = (const float*)d_in[6];
    const float* scalesl = (const float*)d_in[7];
    const float* rots    = (const float*)d_in[8];
    const float* rotsl   = (const float*)d_in[9];
    const float* V       = (const float*)d_in[10];
    const float* P       = (const float*)d_in[11];
    const float* bg      = (const float*)d_in[12];
    // d_in[13] = campos (unused)

    float* out = (float*)d_out;
    float* ws  = (float*)d_ws;

    hipLaunchKernelGGL(k_pre, dim3(8), dim3(256), 0, stream,
                       means3D, colors, lang, opac, opacl, scales, scalesl,
                       rots, rotsl, V, P, ws, out);
    hipLaunchKernelGGL(k_render, dim3(256, 2), dim3(64), 0, stream,
                       ws, bg, out);
}

// Round 8
// 114.836 us; speedup vs baseline: 1.3551x; 1.0340x over previous
//
#include <hip/hip_runtime.h>
#include <math.h>

#define N_G 1024
#define HW 128
#define NPIX (HW * HW)

// d_out offsets (flat float output, reference return order)
#define OFF_COLOR  0                        // (3,128,128)
#define OFF_LANG   49152                    // (8,128,128)
#define OFF_RADII  180224                   // (1024,)
#define OFF_RADIIL 181248                   // (1024,)
#define OFF_DEPTH  182272                   // (1,128,128)
#define OFF_OPAC   198656                   // (1,128,128)
#define OFF_OPACL  215040                   // (1,128,128)
#define OFF_NT     231424                   // (1024,)
#define OFF_NTL    232448                   // (1024,)

// ws layout (floats), all arrays indexed by ORIGINAL gaussian id (no global sort):
//  REC[r][n]  : 16 floats (4x float4): [px,py,ca,cb][cc,op,pm,tz][f0..3][f4..7]
//  SCAN[r][n] : float4 {px,py,bx,by}  (bbox half-extents, exact support + 2px)
//  KEY[r][n]  : u64 = (float_bits(valid?tz:inf) << 32) | n   -- unique, argsort-stable
#define WS_REC(r)   ((r) * 16 * N_G)
#define WS_SCAN(r)  (32 * N_G + (r) * 4 * N_G)
#define WS_KEY(r)   (40 * N_G + (r) * 2 * N_G)
// total: 44 * N_G floats = 176 KiB of d_ws

// ---------------------------------------------------------------------------
// Per-gaussian preprocess, fully parallel (2048 independent threads)
// ---------------------------------------------------------------------------
__global__ __launch_bounds__(256) void k_pre(
    const float* __restrict__ means3D,
    const float* __restrict__ colors, const float* __restrict__ lang,
    const float* __restrict__ opac, const float* __restrict__ opacl,
    const float* __restrict__ scales, const float* __restrict__ scalesl,
    const float* __restrict__ rots, const float* __restrict__ rotsl,
    const float* __restrict__ V, const float* __restrict__ P,
    float* __restrict__ ws, float* __restrict__ out)
{
    int idx = blockIdx.x * 256 + threadIdx.x;
    if (idx >= 2 * N_G) return;
    int r = idx >> 10;           // 0 = color pass, 1 = language pass
    int n = idx & (N_G - 1);
    const float* sc = r ? scalesl : scales;
    const float* qt = r ? rotsl : rots;
    const float* op = r ? opacl : opac;
    const float* ft = r ? lang : colors;
    int F = r ? 8 : 3;

    float m0 = means3D[n * 3 + 0], m1 = means3D[n * 3 + 1], m2 = means3D[n * 3 + 2];
    // t = [m,1] @ V  (row-vector times row-major 4x4)
    float t0 = m0 * V[0] + m1 * V[4] + m2 * V[8]  + V[12];
    float t1 = m0 * V[1] + m1 * V[5] + m2 * V[9]  + V[13];
    float tz = m0 * V[2] + m1 * V[6] + m2 * V[10] + V[14];
    // ph = [m,1] @ P
    float ph0 = m0 * P[0] + m1 * P[4] + m2 * P[8]  + P[12];
    float ph1 = m0 * P[1] + m1 * P[5] + m2 * P[9]  + P[13];
    float ph3 = m0 * P[3] + m1 * P[7] + m2 * P[11] + P[15];
    float pw = 1.0f / (ph3 + 1e-7f);
    float px = ((ph0 * pw + 1.0f) * (float)HW - 1.0f) * 0.5f;
    float py = ((ph1 * pw + 1.0f) * (float)HW - 1.0f) * 0.5f;

    // quaternion -> rotation
    float q0 = qt[n * 4 + 0], q1 = qt[n * 4 + 1], q2 = qt[n * 4 + 2], q3 = qt[n * 4 + 3];
    float qinv = 1.0f / sqrtf(q0 * q0 + q1 * q1 + q2 * q2 + q3 * q3);
    q0 *= qinv; q1 *= qinv; q2 *= qinv; q3 *= qinv;
    float rr = q0, x = q1, y = q2, z = q3;
    float R0 = 1.0f - 2.0f * (y * y + z * z), R1 = 2.0f * (x * y - rr * z), R2 = 2.0f * (x * z + rr * y);
    float R3 = 2.0f * (x * y + rr * z), R4 = 1.0f - 2.0f * (x * x + z * z), R5 = 2.0f * (y * z - rr * x);
    float R6 = 2.0f * (x * z - rr * y), R7 = 2.0f * (y * z + rr * x), R8 = 1.0f - 2.0f * (x * x + y * y);
    float s0 = sc[n * 3 + 0], s1 = sc[n * 3 + 1], s2 = sc[n * 3 + 2]; // SCALE_MOD = 1
    float M0 = R0 * s0, M1 = R1 * s1, M2 = R2 * s2;
    float M3 = R3 * s0, M4 = R4 * s1, M5 = R5 * s2;
    float M6 = R6 * s0, M7 = R7 * s1, M8 = R8 * s2;
    // cov3d = M M^T (symmetric)
    float c300 = M0 * M0 + M1 * M1 + M2 * M2;
    float c301 = M0 * M3 + M1 * M4 + M2 * M5;
    float c302 = M0 * M6 + M1 * M7 + M2 * M8;
    float c311 = M3 * M3 + M4 * M4 + M5 * M5;
    float c312 = M3 * M6 + M4 * M7 + M5 * M8;
    float c322 = M6 * M6 + M7 * M7 + M8 * M8;

    const float fx = (float)HW / (2.0f * 0.7f);
    const float fy = fx;
    const float limx = 1.3f * 0.7f, limy = 1.3f * 0.7f;
    float txz = fminf(fmaxf(t0 / tz, -limx), limx) * tz;
    float tyz = fminf(fmaxf(t1 / tz, -limy), limy) * tz;
    float J00 = fx / tz, J02 = -fx * txz / (tz * tz);
    float J11 = fy / tz, J12 = -fy * tyz / (tz * tz);
    // T2 = J @ Wr, Wr[i][j] = V[j*4+i]
    float a0 = J00 * V[0] + J02 * V[2];
    float a1 = J00 * V[4] + J02 * V[6];
    float a2 = J00 * V[8] + J02 * V[10];
    float b0 = J11 * V[1] + J12 * V[2];
    float b1 = J11 * V[5] + J12 * V[6];
    float b2 = J11 * V[9] + J12 * V[10];
    // cov2 = T2 cov3d T2^T + 0.3 I
    float u0 = c300 * a0 + c301 * a1 + c302 * a2;
    float u1 = c301 * a0 + c311 * a1 + c312 * a2;
    float u2 = c302 * a0 + c312 * a1 + c322 * a2;
    float v0 = c300 * b0 + c301 * b1 + c302 * b2;
    float v1 = c301 * b0 + c311 * b1 + c312 * b2;
    float v2 = c302 * b0 + c312 * b1 + c322 * b2;
    float c00 = a0 * u0 + a1 * u1 + a2 * u2 + 0.3f;
    float c01 = b0 * u0 + b1 * u1 + b2 * u2;
    float c11 = b0 * v0 + b1 * v1 + b2 * v2 + 0.3f;

    float det = c00 * c11 - c01 * c01;
    float invdet = 1.0f / (det + 1e-12f);
    float ca = c11 * invdet, cb = -c01 * invdet, cc = c00 * invdet;
    float mid = 0.5f * (c00 + c11);
    float lam1 = mid + sqrtf(fmaxf(0.1f, mid * mid - det));
    bool valid = (tz > 0.2f) && (det > 0.0f);
    float radf = valid ? ceilf(3.0f * sqrtf(lam1)) : 0.0f;
    float o = op[n];
    float opEff = valid ? o : 0.0f;           // folds 'valid' into alpha == 0
    float pmin, bx, by;
    if (opEff > 0.0f) {
        pmin = -logf(255.0f * opEff);         // alpha >= 1/255  <=>  power >= pmin
        float Q = -2.0f * pmin;               // support: q(d) <= Q (exact ellipse)
        if (Q > 0.0f) {
            bx = sqrtf(Q * c00) + 2.0f;       // exact axis extent sqrt(Q*cov2_00) + 2px
            by = sqrtf(Q * c11) + 2.0f;
        } else { bx = -1e30f; by = -1e30f; }  // op <= 1/255: empty support
    } else {
        pmin = __builtin_inff();
        bx = -1e30f; by = -1e30f;             // never hits any tile
    }

    float f8[8];
    #pragma unroll
    for (int f = 0; f < 8; ++f) f8[f] = (f < F) ? ft[n * F + f] : 0.0f;

    float* rec = ws + WS_REC(r) + n * 16;
    ((float4*)rec)[0] = make_float4(px, py, ca, cb);
    ((float4*)rec)[1] = make_float4(cc, opEff, pmin, tz);
    ((float4*)rec)[2] = make_float4(f8[0], f8[1], f8[2], f8[3]);
    ((float4*)rec)[3] = make_float4(f8[4], f8[5], f8[6], f8[7]);
    ((float4*)(ws + WS_SCAN(r)))[n] = make_float4(px, py, bx, by);

    // unique sort key: positive-float bit order == value order; index => stable
    float keyf = valid ? tz : __builtin_inff();
    ((unsigned long long*)(ws + WS_KEY(r)))[n] =
        ((unsigned long long)__float_as_uint(keyf) << 32) | (unsigned)n;

    out[(r ? OFF_RADIIL : OFF_RADII) + n] = radf;
    out[(r ? OFF_NTL : OFF_NT) + n] = 0.0f;   // zero-init for render atomics
}

// ---------------------------------------------------------------------------
// Per-tile render: cull -> local depth rank-sort -> register-shuffle blend
// one 64-thread block (1 wave) per 8x8 pixel tile; grid (256 tiles, 2 passes)
// ---------------------------------------------------------------------------
__global__ __launch_bounds__(64) void k_render(
    const float* __restrict__ ws, const float* __restrict__ bg,
    float* __restrict__ out)
{
    int r = (int)blockIdx.y;
    int tile = (int)blockIdx.x;
    int t = (int)threadIdx.x;
    int tx = t & 7, ty = t >> 3;
    int x0 = (tile & 15) * 8, y0 = (tile >> 4) * 8;
    int px_i = x0 + tx, py_i = y0 + ty;
    float fpx = (float)px_i, fpy = (float)py_i;
    float xmin = (float)x0, xmax = (float)(x0 + 7);
    float ymin = (float)y0, ymax = (float)(y0 + 7);

    __shared__ int s_idx[N_G];
    __shared__ unsigned long long s_key[N_G];
    __shared__ int s_ord[N_G];

    // ---- phase 1: cull. bbox + key loads all in flight (one latency) ----
    const float4* sc4 = (const float4*)(ws + WS_SCAN(r));
    const unsigned long long* keyp = (const unsigned long long*)(ws + WS_KEY(r));
    float4 gv[16];
    unsigned long long kv[16];
    #pragma unroll
    for (int c = 0; c < 16; ++c) { gv[c] = sc4[c * 64 + t]; kv[c] = keyp[c * 64 + t]; }

    int cnt = 0;
    #pragma unroll
    for (int c = 0; c < 16; ++c) {
        float gpx = gv[c].x, gpy = gv[c].y, gbx = gv[c].z, gby = gv[c].w;
        bool hit = (gpx - gbx <= xmax) && (gpx + gbx >= xmin) &&
                   (gpy - gby <= ymax) && (gpy + gby >= ymin);
        unsigned long long m = __ballot(hit);
        if (hit) {
            int off = __popcll(m & ((1ull << t) - 1ull));
            s_idx[cnt + off] = c * 64 + t;
            s_key[cnt + off] = kv[c];
        }
        cnt += __popcll(m);
    }
    __syncthreads();

    // ---- phase 2: local rank sort (keys unique; unrolled -> loads in flight) ----
    for (int k = t; k < cnt; k += 64) {
        unsigned long long my = s_key[k];
        int rank = 0;
        #pragma unroll 8
        for (int j = 0; j < cnt; ++j) rank += (s_key[j] < my) ? 1 : 0;
        s_ord[rank] = s_idx[k];
    }
    __syncthreads();

    // ---- phase 3: blend. chunk staged in per-lane regs, broadcast via shfl ----
    float T = 1.0f;
    float acc[8] = {0, 0, 0, 0, 0, 0, 0, 0};
    float dacc = 0.0f;
    const float ONE255 = 1.0f / 255.0f;
    int ntbase = r ? OFF_NTL : OFF_NT;

    for (int b = 0; b < cnt; b += 64) {
        int jmax = min(64, cnt - b);
        float4 A = make_float4(0, 0, 0, 0), B = A, C = A, D = A;
        int gi = 0;
        if (t < jmax) {
            gi = s_ord[b + t];
            const float4* gp = (const float4*)(ws + WS_REC(r) + gi * 16);
            A = gp[0]; B = gp[1]; C = gp[2]; D = gp[3];
        }

        for (int j = 0; j < jmax; ++j) {
            float pxj = __shfl(A.x, j), pyj = __shfl(A.y, j);
            float caj = __shfl(A.z, j), cbj = __shfl(A.w, j);
            float ccj = __shfl(B.x, j), opj = __shfl(B.y, j), pmj = __shfl(B.z, j);
            float dx = pxj - fpx, dy = pyj - fpy;
            float power = -0.5f * (caj * dx * dx + ccj * dy * dy) - cbj * dx * dy;
            float alpha = 0.0f;
            // conservative precheck gates expf; final decision is exact reference math
            if (power <= 0.0f && power >= pmj - 1e-3f) {
                alpha = fminf(0.99f, opj * expf(power));
                if (alpha < ONE255) alpha = 0.0f;
            }
            unsigned long long m = __ballot(alpha > 0.0f);
            if (m) {
                // wave is fully re-converged here (`m` is uniform): every __shfl
                // below reads from an ACTIVE lane. (Round-4 bug: __shfl(gi, j)
                // sat inside divergent `if (t==0)` -> undefined -> garbage idx.)
                float w = alpha * T;
                float f0 = __shfl(C.x, j), f1 = __shfl(C.y, j), f2 = __shfl(C.z, j);
                int origj = __shfl(gi, j);
                if (r == 0) {
                    acc[0] += w * f0; acc[1] += w * f1; acc[2] += w * f2;
                    dacc   += w * __shfl(B.w, j);
                } else {
                    float f3 = __shfl(C.w, j);
                    float f4 = __shfl(D.x, j), f5 = __shfl(D.y, j);
                    float f6 = __shfl(D.z, j), f7 = __shfl(D.w, j);
                    acc[0] += w * f0; acc[1] += w * f1; acc[2] += w * f2; acc[3] += w * f3;
                    acc[4] += w * f4; acc[5] += w * f5; acc[6] += w * f6; acc[7] += w * f7;
                }
                T *= (1.0f - alpha);
                if (t == 0) {
                    atomicAdd(&out[ntbase + origj], (float)__popcll(m));
                }
            }
        }
    }

    int p = py_i * HW + px_i;
    if (r == 0) {
        out[OFF_COLOR + 0 * NPIX + p] = acc[0] + T * bg[0];
        out[OFF_COLOR + 1 * NPIX + p] = acc[1] + T * bg[1];
        out[OFF_COLOR + 2 * NPIX + p] = acc[2] + T * bg[2];
        out[OFF_DEPTH + p] = dacc;
        out[OFF_OPAC + p] = 1.0f - T;
    } else {
        #pragma unroll
        for (int f = 0; f < 8; ++f)
            out[OFF_LANG + f * NPIX + p] = acc[f];
        out[OFF_OPACL + p] = 1.0f - T;
    }
}

extern "C" void kernel_launch(void* const* d_in, const int* in_sizes, int n_in,
                              void* d_out, int out_size, void* d_ws, size_t ws_size,
                              hipStream_t stream)
{
    const float* means3D = (const float*)d_in[0];
    // d_in[1] = means2D (unused)
    const float* colors  = (const float*)d_in[2];
    const float* lang    = (const float*)d_in[3];
    const float* opac    = (const float*)d_in[4];
    const float* opacl   = (const float*)d_in[5];
    const float* scales  = (const float*)d_in[6];
    const float* scalesl = (const float*)d_in[7];
    const float* rots    = (const float*)d_in[8];
    const float* rotsl   = (const float*)d_in[9];
    const float* V       = (const float*)d_in[10];
    const float* P       = (const float*)d_in[11];
    const float* bg      = (const float*)d_in[12];
    // d_in[13] = campos (unused)

    float* out = (float*)d_out;
    float* ws  = (float*)d_ws;

    hipLaunchKernelGGL(k_pre, dim3(8), dim3(256), 0, stream,
                       means3D, colors, lang, opac, opacl, scales, scalesl,
                       rots, rotsl, V, P, ws, out);
    hipLaunchKernelGGL(k_render, dim3(256, 2), dim3(64), 0, stream,
                       ws, bg, out);
}

// Round 9
// 95.478 us; speedup vs baseline: 1.6298x; 1.2027x over previous
//
#include <hip/hip_runtime.h>
#include <math.h>

#define N_G 1024
#define HW 128
#define NPIX (HW * HW)

// d_out offsets (flat float output, reference return order)
#define OFF_COLOR  0                        // (3,128,128)
#define OFF_LANG   49152                    // (8,128,128)
#define OFF_RADII  180224                   // (1024,)
#define OFF_RADIIL 181248                   // (1024,)
#define OFF_DEPTH  182272                   // (1,128,128)
#define OFF_OPAC   198656                   // (1,128,128)
#define OFF_OPACL  215040                   // (1,128,128)
#define OFF_NT     231424                   // (1024,)
#define OFF_NTL    232448                   // (1024,)

// ws layout (floats), all arrays indexed by ORIGINAL gaussian id (no global sort):
//  REC[r][n]  : 16 floats (4x float4): [px,py,ca,cb][cc,op,pm,tz][f0..3][f4..7]
//  SCAN[r][n] : float4 {px,py,bx,by}  (bbox half-extents, exact support + 2px)
//  KEY[r][n]  : u64 = (float_bits(valid?tz:inf) << 32) | n   -- unique, argsort-stable
#define WS_REC(r)   ((r) * 16 * N_G)
#define WS_SCAN(r)  (32 * N_G + (r) * 4 * N_G)
#define WS_KEY(r)   (40 * N_G + (r) * 2 * N_G)

// ---------------------------------------------------------------------------
// Per-gaussian preprocess, fully parallel (2048 independent threads)
// ---------------------------------------------------------------------------
__global__ __launch_bounds__(256) void k_pre(
    const float* __restrict__ means3D,
    const float* __restrict__ colors, const float* __restrict__ lang,
    const float* __restrict__ opac, const float* __restrict__ opacl,
    const float* __restrict__ scales, const float* __restrict__ scalesl,
    const float* __restrict__ rots, const float* __restrict__ rotsl,
    const float* __restrict__ V, const float* __restrict__ P,
    float* __restrict__ ws, float* __restrict__ out)
{
    int idx = blockIdx.x * 256 + threadIdx.x;
    if (idx >= 2 * N_G) return;
    int r = idx >> 10;           // 0 = color pass, 1 = language pass
    int n = idx & (N_G - 1);
    const float* sc = r ? scalesl : scales;
    const float* qt = r ? rotsl : rots;
    const float* op = r ? opacl : opac;
    const float* ft = r ? lang : colors;
    int F = r ? 8 : 3;

    float m0 = means3D[n * 3 + 0], m1 = means3D[n * 3 + 1], m2 = means3D[n * 3 + 2];
    float t0 = m0 * V[0] + m1 * V[4] + m2 * V[8]  + V[12];
    float t1 = m0 * V[1] + m1 * V[5] + m2 * V[9]  + V[13];
    float tz = m0 * V[2] + m1 * V[6] + m2 * V[10] + V[14];
    float ph0 = m0 * P[0] + m1 * P[4] + m2 * P[8]  + P[12];
    float ph1 = m0 * P[1] + m1 * P[5] + m2 * P[9]  + P[13];
    float ph3 = m0 * P[3] + m1 * P[7] + m2 * P[11] + P[15];
    float pw = 1.0f / (ph3 + 1e-7f);
    float px = ((ph0 * pw + 1.0f) * (float)HW - 1.0f) * 0.5f;
    float py = ((ph1 * pw + 1.0f) * (float)HW - 1.0f) * 0.5f;

    float q0 = qt[n * 4 + 0], q1 = qt[n * 4 + 1], q2 = qt[n * 4 + 2], q3 = qt[n * 4 + 3];
    float qinv = 1.0f / sqrtf(q0 * q0 + q1 * q1 + q2 * q2 + q3 * q3);
    q0 *= qinv; q1 *= qinv; q2 *= qinv; q3 *= qinv;
    float rr = q0, x = q1, y = q2, z = q3;
    float R0 = 1.0f - 2.0f * (y * y + z * z), R1 = 2.0f * (x * y - rr * z), R2 = 2.0f * (x * z + rr * y);
    float R3 = 2.0f * (x * y + rr * z), R4 = 1.0f - 2.0f * (x * x + z * z), R5 = 2.0f * (y * z - rr * x);
    float R6 = 2.0f * (x * z - rr * y), R7 = 2.0f * (y * z + rr * x), R8 = 1.0f - 2.0f * (x * x + y * y);
    float s0 = sc[n * 3 + 0], s1 = sc[n * 3 + 1], s2 = sc[n * 3 + 2];
    float M0 = R0 * s0, M1 = R1 * s1, M2 = R2 * s2;
    float M3 = R3 * s0, M4 = R4 * s1, M5 = R5 * s2;
    float M6 = R6 * s0, M7 = R7 * s1, M8 = R8 * s2;
    float c300 = M0 * M0 + M1 * M1 + M2 * M2;
    float c301 = M0 * M3 + M1 * M4 + M2 * M5;
    float c302 = M0 * M6 + M1 * M7 + M2 * M8;
    float c311 = M3 * M3 + M4 * M4 + M5 * M5;
    float c312 = M3 * M6 + M4 * M7 + M5 * M8;
    float c322 = M6 * M6 + M7 * M7 + M8 * M8;

    const float fx = (float)HW / (2.0f * 0.7f);
    const float fy = fx;
    const float limx = 1.3f * 0.7f, limy = 1.3f * 0.7f;
    float txz = fminf(fmaxf(t0 / tz, -limx), limx) * tz;
    float tyz = fminf(fmaxf(t1 / tz, -limy), limy) * tz;
    float J00 = fx / tz, J02 = -fx * txz / (tz * tz);
    float J11 = fy / tz, J12 = -fy * tyz / (tz * tz);
    float a0 = J00 * V[0] + J02 * V[2];
    float a1 = J00 * V[4] + J02 * V[6];
    float a2 = J00 * V[8] + J02 * V[10];
    float b0 = J11 * V[1] + J12 * V[2];
    float b1 = J11 * V[5] + J12 * V[6];
    float b2 = J11 * V[9] + J12 * V[10];
    float u0 = c300 * a0 + c301 * a1 + c302 * a2;
    float u1 = c301 * a0 + c311 * a1 + c312 * a2;
    float u2 = c302 * a0 + c312 * a1 + c322 * a2;
    float v0 = c300 * b0 + c301 * b1 + c302 * b2;
    float v1 = c301 * b0 + c311 * b1 + c312 * b2;
    float v2 = c302 * b0 + c312 * b1 + c322 * b2;
    float c00 = a0 * u0 + a1 * u1 + a2 * u2 + 0.3f;
    float c01 = b0 * u0 + b1 * u1 + b2 * u2;
    float c11 = b0 * v0 + b1 * v1 + b2 * v2 + 0.3f;

    float det = c00 * c11 - c01 * c01;
    float invdet = 1.0f / (det + 1e-12f);
    float ca = c11 * invdet, cb = -c01 * invdet, cc = c00 * invdet;
    float mid = 0.5f * (c00 + c11);
    float lam1 = mid + sqrtf(fmaxf(0.1f, mid * mid - det));
    bool valid = (tz > 0.2f) && (det > 0.0f);
    float radf = valid ? ceilf(3.0f * sqrtf(lam1)) : 0.0f;
    float o = op[n];
    float opEff = valid ? o : 0.0f;
    float pmin, bx, by;
    if (opEff > 0.0f) {
        pmin = -logf(255.0f * opEff);
        float Q = -2.0f * pmin;
        if (Q > 0.0f) {
            bx = sqrtf(Q * c00) + 2.0f;
            by = sqrtf(Q * c11) + 2.0f;
        } else { bx = -1e30f; by = -1e30f; }
    } else {
        pmin = __builtin_inff();
        bx = -1e30f; by = -1e30f;
    }

    float f8[8];
    #pragma unroll
    for (int f = 0; f < 8; ++f) f8[f] = (f < F) ? ft[n * F + f] : 0.0f;

    float* rec = ws + WS_REC(r) + n * 16;
    ((float4*)rec)[0] = make_float4(px, py, ca, cb);
    ((float4*)rec)[1] = make_float4(cc, opEff, pmin, tz);
    ((float4*)rec)[2] = make_float4(f8[0], f8[1], f8[2], f8[3]);
    ((float4*)rec)[3] = make_float4(f8[4], f8[5], f8[6], f8[7]);
    ((float4*)(ws + WS_SCAN(r)))[n] = make_float4(px, py, bx, by);

    float keyf = valid ? tz : __builtin_inff();
    ((unsigned long long*)(ws + WS_KEY(r)))[n] =
        ((unsigned long long)__float_as_uint(keyf) << 32) | (unsigned)n;

    out[(r ? OFF_RADIIL : OFF_RADII) + n] = radf;
    out[(r ? OFF_NTL : OFF_NT) + n] = 0.0f;
}

// ---------------------------------------------------------------------------
// Per-tile render, 4 waves/block. Cull (parallel) -> sort -> segmented blend
// (compositing is associative: acc = acc0 + T0*(acc1 + T1*(acc2 + T2*acc3)))
// grid (256 tiles, 2 passes) x 256 threads; lane = pixel in all waves.
// ---------------------------------------------------------------------------
__global__ __launch_bounds__(256) void k_render(
    const float* __restrict__ ws, const float* __restrict__ bg,
    float* __restrict__ out)
{
    int r = (int)blockIdx.y;
    int tile = (int)blockIdx.x;
    int tid = (int)threadIdx.x;
    int w = tid >> 6;            // wave 0..3
    int t = tid & 63;            // lane = pixel within 8x8 tile
    int tx = t & 7, ty = t >> 3;
    int x0 = (tile & 15) * 8, y0 = (tile >> 4) * 8;
    int px_i = x0 + tx, py_i = y0 + ty;
    float fpx = (float)px_i, fpy = (float)py_i;
    float xmin = (float)x0, xmax = (float)(x0 + 7);
    float ymin = (float)y0, ymax = (float)(y0 + 7);

    __shared__ int s_idx[N_G];
    __shared__ unsigned long long s_key[N_G];
    __shared__ int s_ord[N_G];
    __shared__ int s_hw[4];
    __shared__ float s_comb[4][10][64];   // [wave][0..7 acc, 8 dacc, 9 T][pixel]

    // ---- cull: wave w scans chunks 4w..4w+3 (all loads in flight) ----
    const float4* sc4 = (const float4*)(ws + WS_SCAN(r));
    const unsigned long long* keyp = (const unsigned long long*)(ws + WS_KEY(r));
    float4 gv[4];
    unsigned long long kv[4];
    #pragma unroll
    for (int c4 = 0; c4 < 4; ++c4) {
        int c = 4 * w + c4;
        gv[c4] = sc4[c * 64 + t];
        kv[c4] = keyp[c * 64 + t];
    }
    bool hb[4];
    unsigned long long m4[4];
    int hsum = 0;
    #pragma unroll
    for (int c4 = 0; c4 < 4; ++c4) {
        float gpx = gv[c4].x, gpy = gv[c4].y, gbx = gv[c4].z, gby = gv[c4].w;
        hb[c4] = (gpx - gbx <= xmax) && (gpx + gbx >= xmin) &&
                 (gpy - gby <= ymax) && (gpy + gby >= ymin);
        m4[c4] = __ballot(hb[c4]);
        hsum += __popcll(m4[c4]);
    }
    if (t == 0) s_hw[w] = hsum;
    __syncthreads();
    int start = 0;
    #pragma unroll
    for (int w2 = 0; w2 < 4; ++w2) start += (w2 < w) ? s_hw[w2] : 0;
    int cnt = s_hw[0] + s_hw[1] + s_hw[2] + s_hw[3];
    unsigned long long lmask = (1ull << t) - 1ull;
    int off = start;
    #pragma unroll
    for (int c4 = 0; c4 < 4; ++c4) {
        if (hb[c4]) {
            int o = off + __popcll(m4[c4] & lmask);
            s_idx[o] = (4 * w + c4) * 64 + t;
            s_key[o] = kv[c4];
        }
        off += __popcll(m4[c4]);
    }
    __syncthreads();

    // ---- rank sort over 256 threads (keys unique -> stable argsort) ----
    for (int k = tid; k < cnt; k += 256) {
        unsigned long long my = s_key[k];
        int rank = 0;
        #pragma unroll 8
        for (int j = 0; j < cnt; ++j) rank += (s_key[j] < my) ? 1 : 0;
        s_ord[rank] = s_idx[k];
    }
    __syncthreads();

    // ---- segmented blend: wave w owns sorted slots [w*seg, min(cnt,(w+1)*seg)) ----
    int seg = (cnt + 3) >> 2;
    int sA = min(cnt, w * seg);
    int sB = min(cnt, sA + seg);
    float T = 1.0f;
    float acc[8] = {0, 0, 0, 0, 0, 0, 0, 0};
    float dacc = 0.0f;
    const float ONE255 = 1.0f / 255.0f;
    int ntbase = r ? OFF_NTL : OFF_NT;

    for (int b = sA; b < sB; b += 64) {
        int jmax = min(64, sB - b);
        float4 A = make_float4(0, 0, 0, 0), B = A, C = A, D = A;
        int gi = 0;
        if (t < jmax) {
            gi = s_ord[b + t];
            const float4* gp = (const float4*)(ws + WS_REC(r) + gi * 16);
            A = gp[0]; B = gp[1]; C = gp[2]; D = gp[3];
        }
        float pcmine = 0.0f;   // popcount for slot b+t (captured when j==t)

        #pragma unroll 4
        for (int j = 0; j < jmax; ++j) {
            float pxj = __shfl(A.x, j), pyj = __shfl(A.y, j);
            float caj = __shfl(A.z, j), cbj = __shfl(A.w, j);
            float ccj = __shfl(B.x, j), opj = __shfl(B.y, j);
            float dx = pxj - fpx, dy = pyj - fpy;
            float power = -0.5f * (caj * dx * dx + ccj * dy * dy) - cbj * dx * dy;
            // branchless exact reference semantics:
            // alpha = min(.99, op*exp(p)); zero if p>0 or alpha<1/255.
            float a1 = fminf(0.99f, opj * expf(power));
            float alpha = (power <= 0.0f && a1 >= ONE255) ? a1 : 0.0f;
            unsigned long long m = __ballot(alpha > 0.0f);
            pcmine = (j == t) ? (float)__popcll(m) : pcmine;
            float wgt = alpha * T;
            float f0 = __shfl(C.x, j), f1 = __shfl(C.y, j), f2 = __shfl(C.z, j);
            if (r == 0) {
                acc[0] += wgt * f0; acc[1] += wgt * f1; acc[2] += wgt * f2;
                dacc   += wgt * __shfl(B.w, j);
            } else {
                float f3 = __shfl(C.w, j);
                float f4 = __shfl(D.x, j), f5 = __shfl(D.y, j);
                float f6 = __shfl(D.z, j), f7 = __shfl(D.w, j);
                acc[0] += wgt * f0; acc[1] += wgt * f1; acc[2] += wgt * f2; acc[3] += wgt * f3;
                acc[4] += wgt * f4; acc[5] += wgt * f5; acc[6] += wgt * f6; acc[7] += wgt * f7;
            }
            T *= (1.0f - alpha);
        }
        // one atomic per hit-slot, after the loop (no shuffles below -> safe)
        if (pcmine > 0.0f) atomicAdd(&out[ntbase + gi], pcmine);
    }

    // ---- per-pixel cross-wave combine (front-to-back over segments) ----
    #pragma unroll
    for (int c = 0; c < 8; ++c) s_comb[w][c][t] = acc[c];
    s_comb[w][8][t] = dacc;
    s_comb[w][9][t] = T;
    __syncthreads();

    if (w == 0) {
        float oc[8], od, Tq;
        #pragma unroll
        for (int c = 0; c < 8; ++c) oc[c] = s_comb[0][c][t];
        od = s_comb[0][8][t];
        Tq = s_comb[0][9][t];
        #pragma unroll
        for (int w2 = 1; w2 < 4; ++w2) {
            #pragma unroll
            for (int c = 0; c < 8; ++c) oc[c] += Tq * s_comb[w2][c][t];
            od += Tq * s_comb[w2][8][t];
            Tq *= s_comb[w2][9][t];
        }
        int p = py_i * HW + px_i;
        if (r == 0) {
            out[OFF_COLOR + 0 * NPIX + p] = oc[0] + Tq * bg[0];
            out[OFF_COLOR + 1 * NPIX + p] = oc[1] + Tq * bg[1];
            out[OFF_COLOR + 2 * NPIX + p] = oc[2] + Tq * bg[2];
            out[OFF_DEPTH + p] = od;
            out[OFF_OPAC + p] = 1.0f - Tq;
        } else {
            #pragma unroll
            for (int f = 0; f < 8; ++f)
                out[OFF_LANG + f * NPIX + p] = oc[f];
            out[OFF_OPACL + p] = 1.0f - Tq;
        }
    }
}

extern "C" void kernel_launch(void* const* d_in, const int* in_sizes, int n_in,
                              void* d_out, int out_size, void* d_ws, size_t ws_size,
                              hipStream_t stream)
{
    const float* means3D = (const float*)d_in[0];
    const float* colors  = (const float*)d_in[2];
    const float* lang    = (const float*)d_in[3];
    const float* opac    = (const float*)d_in[4];
    const float* opacl   = (const float*)d_in[5];
    const float* scales  = (const float*)d_in[6];
    const float* scalesl = (const float*)d_in[7];
    const float* rots    = (const float*)d_in[8];
    const float* rotsl   = (const float*)d_in[9];
    const float* V       = (const float*)d_in[10];
    const float* P       = (const float*)d_in[11];
    const float* bg      = (const float*)d_in[12];

    float* out = (float*)d_out;
    float* ws  = (float*)d_ws;

    hipLaunchKernelGGL(k_pre, dim3(8), dim3(256), 0, stream,
                       means3D, colors, lang, opac, opacl, scales, scalesl,
                       rots, rotsl, V, P, ws, out);
    hipLaunchKernelGGL(k_render, dim3(256, 2), dim3(256), 0, stream,
                       ws, bg, out);
}

// Round 10
// 93.689 us; speedup vs baseline: 1.6609x; 1.0191x over previous
//
#include <hip/hip_runtime.h>
#include <math.h>

#define N_G 1024
#define HW 128
#define NPIX (HW * HW)
#define NWAVE 8                 // segments (waves) per render block

// d_out offsets (flat float output, reference return order)
#define OFF_COLOR  0                        // (3,128,128)
#define OFF_LANG   49152                    // (8,128,128)
#define OFF_RADII  180224                   // (1024,)
#define OFF_RADIIL 181248                   // (1024,)
#define OFF_DEPTH  182272                   // (1,128,128)
#define OFF_OPAC   198656                   // (1,128,128)
#define OFF_OPACL  215040                   // (1,128,128)
#define OFF_NT     231424                   // (1024,)
#define OFF_NTL    232448                   // (1024,)

// ws layout (floats), all arrays indexed by ORIGINAL gaussian id (no global sort):
//  REC[r][n]  : 16 floats (4x float4): [px,py,ca,cb][cc,op,pm,tz][f0..3][f4..7]
//  SCAN[r][n] : float4 {px,py,bx,by}  (bbox half-extents, exact support + 2px)
//  KEY[r][n]  : u64 = (float_bits(valid?tz:inf) << 32) | n   -- unique, argsort-stable
#define WS_REC(r)   ((r) * 16 * N_G)
#define WS_SCAN(r)  (32 * N_G + (r) * 4 * N_G)
#define WS_KEY(r)   (40 * N_G + (r) * 2 * N_G)

// ---------------------------------------------------------------------------
// Per-gaussian preprocess, fully parallel (2048 independent threads)
// ---------------------------------------------------------------------------
__global__ __launch_bounds__(256) void k_pre(
    const float* __restrict__ means3D,
    const float* __restrict__ colors, const float* __restrict__ lang,
    const float* __restrict__ opac, const float* __restrict__ opacl,
    const float* __restrict__ scales, const float* __restrict__ scalesl,
    const float* __restrict__ rots, const float* __restrict__ rotsl,
    const float* __restrict__ V, const float* __restrict__ P,
    float* __restrict__ ws, float* __restrict__ out)
{
    int idx = blockIdx.x * 256 + threadIdx.x;
    if (idx >= 2 * N_G) return;
    int r = idx >> 10;           // 0 = color pass, 1 = language pass
    int n = idx & (N_G - 1);
    const float* sc = r ? scalesl : scales;
    const float* qt = r ? rotsl : rots;
    const float* op = r ? opacl : opac;
    const float* ft = r ? lang : colors;
    int F = r ? 8 : 3;

    float m0 = means3D[n * 3 + 0], m1 = means3D[n * 3 + 1], m2 = means3D[n * 3 + 2];
    float t0 = m0 * V[0] + m1 * V[4] + m2 * V[8]  + V[12];
    float t1 = m0 * V[1] + m1 * V[5] + m2 * V[9]  + V[13];
    float tz = m0 * V[2] + m1 * V[6] + m2 * V[10] + V[14];
    float ph0 = m0 * P[0] + m1 * P[4] + m2 * P[8]  + P[12];
    float ph1 = m0 * P[1] + m1 * P[5] + m2 * P[9]  + P[13];
    float ph3 = m0 * P[3] + m1 * P[7] + m2 * P[11] + P[15];
    float pw = 1.0f / (ph3 + 1e-7f);
    float px = ((ph0 * pw + 1.0f) * (float)HW - 1.0f) * 0.5f;
    float py = ((ph1 * pw + 1.0f) * (float)HW - 1.0f) * 0.5f;

    float q0 = qt[n * 4 + 0], q1 = qt[n * 4 + 1], q2 = qt[n * 4 + 2], q3 = qt[n * 4 + 3];
    float qinv = 1.0f / sqrtf(q0 * q0 + q1 * q1 + q2 * q2 + q3 * q3);
    q0 *= qinv; q1 *= qinv; q2 *= qinv; q3 *= qinv;
    float rr = q0, x = q1, y = q2, z = q3;
    float R0 = 1.0f - 2.0f * (y * y + z * z), R1 = 2.0f * (x * y - rr * z), R2 = 2.0f * (x * z + rr * y);
    float R3 = 2.0f * (x * y + rr * z), R4 = 1.0f - 2.0f * (x * x + z * z), R5 = 2.0f * (y * z - rr * x);
    float R6 = 2.0f * (x * z - rr * y), R7 = 2.0f * (y * z + rr * x), R8 = 1.0f - 2.0f * (x * x + y * y);
    float s0 = sc[n * 3 + 0], s1 = sc[n * 3 + 1], s2 = sc[n * 3 + 2];
    float M0 = R0 * s0, M1 = R1 * s1, M2 = R2 * s2;
    float M3 = R3 * s0, M4 = R4 * s1, M5 = R5 * s2;
    float M6 = R6 * s0, M7 = R7 * s1, M8 = R8 * s2;
    float c300 = M0 * M0 + M1 * M1 + M2 * M2;
    float c301 = M0 * M3 + M1 * M4 + M2 * M5;
    float c302 = M0 * M6 + M1 * M7 + M2 * M8;
    float c311 = M3 * M3 + M4 * M4 + M5 * M5;
    float c312 = M3 * M6 + M4 * M7 + M5 * M8;
    float c322 = M6 * M6 + M7 * M7 + M8 * M8;

    const float fx = (float)HW / (2.0f * 0.7f);
    const float fy = fx;
    const float limx = 1.3f * 0.7f, limy = 1.3f * 0.7f;
    float txz = fminf(fmaxf(t0 / tz, -limx), limx) * tz;
    float tyz = fminf(fmaxf(t1 / tz, -limy), limy) * tz;
    float J00 = fx / tz, J02 = -fx * txz / (tz * tz);
    float J11 = fy / tz, J12 = -fy * tyz / (tz * tz);
    float a0 = J00 * V[0] + J02 * V[2];
    float a1 = J00 * V[4] + J02 * V[6];
    float a2 = J00 * V[8] + J02 * V[10];
    float b0 = J11 * V[1] + J12 * V[2];
    float b1 = J11 * V[5] + J12 * V[6];
    float b2 = J11 * V[9] + J12 * V[10];
    float u0 = c300 * a0 + c301 * a1 + c302 * a2;
    float u1 = c301 * a0 + c311 * a1 + c312 * a2;
    float u2 = c302 * a0 + c312 * a1 + c322 * a2;
    float v0 = c300 * b0 + c301 * b1 + c302 * b2;
    float v1 = c301 * b0 + c311 * b1 + c312 * b2;
    float v2 = c302 * b0 + c312 * b1 + c322 * b2;
    float c00 = a0 * u0 + a1 * u1 + a2 * u2 + 0.3f;
    float c01 = b0 * u0 + b1 * u1 + b2 * u2;
    float c11 = b0 * v0 + b1 * v1 + b2 * v2 + 0.3f;

    float det = c00 * c11 - c01 * c01;
    float invdet = 1.0f / (det + 1e-12f);
    float ca = c11 * invdet, cb = -c01 * invdet, cc = c00 * invdet;
    float mid = 0.5f * (c00 + c11);
    float lam1 = mid + sqrtf(fmaxf(0.1f, mid * mid - det));
    bool valid = (tz > 0.2f) && (det > 0.0f);
    float radf = valid ? ceilf(3.0f * sqrtf(lam1)) : 0.0f;
    float o = op[n];
    float opEff = valid ? o : 0.0f;
    float pmin, bx, by;
    if (opEff > 0.0f) {
        pmin = -logf(255.0f * opEff);
        float Q = -2.0f * pmin;
        if (Q > 0.0f) {
            bx = sqrtf(Q * c00) + 2.0f;
            by = sqrtf(Q * c11) + 2.0f;
        } else { bx = -1e30f; by = -1e30f; }
    } else {
        pmin = __builtin_inff();
        bx = -1e30f; by = -1e30f;
    }

    float f8[8];
    #pragma unroll
    for (int f = 0; f < 8; ++f) f8[f] = (f < F) ? ft[n * F + f] : 0.0f;

    float* rec = ws + WS_REC(r) + n * 16;
    ((float4*)rec)[0] = make_float4(px, py, ca, cb);
    ((float4*)rec)[1] = make_float4(cc, opEff, pmin, tz);
    ((float4*)rec)[2] = make_float4(f8[0], f8[1], f8[2], f8[3]);
    ((float4*)rec)[3] = make_float4(f8[4], f8[5], f8[6], f8[7]);
    ((float4*)(ws + WS_SCAN(r)))[n] = make_float4(px, py, bx, by);

    float keyf = valid ? tz : __builtin_inff();
    ((unsigned long long*)(ws + WS_KEY(r)))[n] =
        ((unsigned long long)__float_as_uint(keyf) << 32) | (unsigned)n;

    out[(r ? OFF_RADIIL : OFF_RADII) + n] = radf;
    out[(r ? OFF_NTL : OFF_NT) + n] = 0.0f;
}

// ---------------------------------------------------------------------------
// Per-tile render, NWAVE=8 waves/block. Cull (parallel) -> sort -> segmented
// blend (compositing is associative: acc = acc0 + T0*(acc1 + T1*(...)))
// grid (256 tiles, 2 passes) x 512 threads; lane = pixel in all waves.
// ---------------------------------------------------------------------------
__global__ __launch_bounds__(64 * NWAVE) void k_render(
    const float* __restrict__ ws, const float* __restrict__ bg,
    float* __restrict__ out)
{
    int r = (int)blockIdx.y;
    int tile = (int)blockIdx.x;
    int tid = (int)threadIdx.x;
    int w = tid >> 6;            // wave 0..NWAVE-1
    int t = tid & 63;            // lane = pixel within 8x8 tile
    int tx = t & 7, ty = t >> 3;
    int x0 = (tile & 15) * 8, y0 = (tile >> 4) * 8;
    int px_i = x0 + tx, py_i = y0 + ty;
    float fpx = (float)px_i, fpy = (float)py_i;
    float xmin = (float)x0, xmax = (float)(x0 + 7);
    float ymin = (float)y0, ymax = (float)(y0 + 7);

    const int CPW = 16 / NWAVE;  // scan chunks per wave

    __shared__ int s_idx[N_G];
    __shared__ unsigned long long s_key[N_G];
    __shared__ int s_ord[N_G];
    __shared__ int s_hw[NWAVE];
    __shared__ float s_comb[NWAVE][10][64];   // [wave][0..7 acc, 8 dacc, 9 T][pixel]

    // ---- cull: wave w scans chunks CPW*w .. CPW*w+CPW-1 (loads in flight) ----
    const float4* sc4 = (const float4*)(ws + WS_SCAN(r));
    const unsigned long long* keyp = (const unsigned long long*)(ws + WS_KEY(r));
    float4 gv[CPW];
    unsigned long long kv[CPW];
    #pragma unroll
    for (int c4 = 0; c4 < CPW; ++c4) {
        int c = CPW * w + c4;
        gv[c4] = sc4[c * 64 + t];
        kv[c4] = keyp[c * 64 + t];
    }
    bool hb[CPW];
    unsigned long long m4[CPW];
    int hsum = 0;
    #pragma unroll
    for (int c4 = 0; c4 < CPW; ++c4) {
        float gpx = gv[c4].x, gpy = gv[c4].y, gbx = gv[c4].z, gby = gv[c4].w;
        hb[c4] = (gpx - gbx <= xmax) && (gpx + gbx >= xmin) &&
                 (gpy - gby <= ymax) && (gpy + gby >= ymin);
        m4[c4] = __ballot(hb[c4]);
        hsum += __popcll(m4[c4]);
    }
    if (t == 0) s_hw[w] = hsum;
    __syncthreads();
    int start = 0, cnt = 0;
    #pragma unroll
    for (int w2 = 0; w2 < NWAVE; ++w2) {
        int h = s_hw[w2];
        start += (w2 < w) ? h : 0;
        cnt += h;
    }
    unsigned long long lmask = (1ull << t) - 1ull;
    int off = start;
    #pragma unroll
    for (int c4 = 0; c4 < CPW; ++c4) {
        if (hb[c4]) {
            int o = off + __popcll(m4[c4] & lmask);
            s_idx[o] = (CPW * w + c4) * 64 + t;
            s_key[o] = kv[c4];
        }
        off += __popcll(m4[c4]);
    }
    __syncthreads();

    // ---- rank sort over all threads (keys unique -> stable argsort) ----
    for (int k = tid; k < cnt; k += 64 * NWAVE) {
        unsigned long long my = s_key[k];
        int rank = 0;
        #pragma unroll 8
        for (int j = 0; j < cnt; ++j) rank += (s_key[j] < my) ? 1 : 0;
        s_ord[rank] = s_idx[k];
    }
    __syncthreads();

    // ---- segmented blend: wave w owns sorted slots [w*seg, min(cnt,(w+1)*seg)) ----
    int seg = (cnt + NWAVE - 1) / NWAVE;
    int sA = min(cnt, w * seg);
    int sB = min(cnt, sA + seg);
    float T = 1.0f;
    float acc[8] = {0, 0, 0, 0, 0, 0, 0, 0};
    float dacc = 0.0f;
    const float ONE255 = 1.0f / 255.0f;
    int ntbase = r ? OFF_NTL : OFF_NT;

    for (int b = sA; b < sB; b += 64) {
        int jmax = min(64, sB - b);
        float4 A = make_float4(0, 0, 0, 0), B = A, C = A, D = A;
        int gi = 0;
        if (t < jmax) {
            gi = s_ord[b + t];
            const float4* gp = (const float4*)(ws + WS_REC(r) + gi * 16);
            A = gp[0]; B = gp[1]; C = gp[2]; D = gp[3];
        }
        float pcmine = 0.0f;   // popcount for slot b+t (captured when j==t)

        #pragma unroll 4
        for (int j = 0; j < jmax; ++j) {
            float pxj = __shfl(A.x, j), pyj = __shfl(A.y, j);
            float caj = __shfl(A.z, j), cbj = __shfl(A.w, j);
            float ccj = __shfl(B.x, j), opj = __shfl(B.y, j);
            float dx = pxj - fpx, dy = pyj - fpy;
            float power = -0.5f * (caj * dx * dx + ccj * dy * dy) - cbj * dx * dy;
            // branchless exact reference semantics:
            // alpha = min(.99, op*exp(p)); zero if p>0 or alpha<1/255.
            float a1 = fminf(0.99f, opj * expf(power));
            float alpha = (power <= 0.0f && a1 >= ONE255) ? a1 : 0.0f;
            unsigned long long m = __ballot(alpha > 0.0f);
            pcmine = (j == t) ? (float)__popcll(m) : pcmine;
            float wgt = alpha * T;
            float f0 = __shfl(C.x, j), f1 = __shfl(C.y, j), f2 = __shfl(C.z, j);
            if (r == 0) {
                acc[0] += wgt * f0; acc[1] += wgt * f1; acc[2] += wgt * f2;
                dacc   += wgt * __shfl(B.w, j);
            } else {
                float f3 = __shfl(C.w, j);
                float f4 = __shfl(D.x, j), f5 = __shfl(D.y, j);
                float f6 = __shfl(D.z, j), f7 = __shfl(D.w, j);
                acc[0] += wgt * f0; acc[1] += wgt * f1; acc[2] += wgt * f2; acc[3] += wgt * f3;
                acc[4] += wgt * f4; acc[5] += wgt * f5; acc[6] += wgt * f6; acc[7] += wgt * f7;
            }
            T *= (1.0f - alpha);
        }
        // one atomic per hit-slot, after the loop (no shuffles below -> safe)
        if (pcmine > 0.0f) atomicAdd(&out[ntbase + gi], pcmine);
    }

    // ---- per-pixel cross-wave combine (front-to-back over segments) ----
    #pragma unroll
    for (int c = 0; c < 8; ++c) s_comb[w][c][t] = acc[c];
    s_comb[w][8][t] = dacc;
    s_comb[w][9][t] = T;
    __syncthreads();

    if (w == 0) {
        float oc[8], od, Tq;
        #pragma unroll
        for (int c = 0; c < 8; ++c) oc[c] = s_comb[0][c][t];
        od = s_comb[0][8][t];
        Tq = s_comb[0][9][t];
        #pragma unroll
        for (int w2 = 1; w2 < NWAVE; ++w2) {
            #pragma unroll
            for (int c = 0; c < 8; ++c) oc[c] += Tq * s_comb[w2][c][t];
            od += Tq * s_comb[w2][8][t];
            Tq *= s_comb[w2][9][t];
        }
        int p = py_i * HW + px_i;
        if (r == 0) {
            out[OFF_COLOR + 0 * NPIX + p] = oc[0] + Tq * bg[0];
            out[OFF_COLOR + 1 * NPIX + p] = oc[1] + Tq * bg[1];
            out[OFF_COLOR + 2 * NPIX + p] = oc[2] + Tq * bg[2];
            out[OFF_DEPTH + p] = od;
            out[OFF_OPAC + p] = 1.0f - Tq;
        } else {
            #pragma unroll
            for (int f = 0; f < 8; ++f)
                out[OFF_LANG + f * NPIX + p] = oc[f];
            out[OFF_OPACL + p] = 1.0f - Tq;
        }
    }
}

extern "C" void kernel_launch(void* const* d_in, const int* in_sizes, int n_in,
                              void* d_out, int out_size, void* d_ws, size_t ws_size,
                              hipStream_t stream)
{
    const float* means3D = (const float*)d_in[0];
    const float* colors  = (const float*)d_in[2];
    const float* lang    = (const float*)d_in[3];
    const float* opac    = (const float*)d_in[4];
    const float* opacl   = (const float*)d_in[5];
    const float* scales  = (const float*)d_in[6];
    const float* scalesl = (const float*)d_in[7];
    const float* rots    = (const float*)d_in[8];
    const float* rotsl   = (const float*)d_in[9];
    const float* V       = (const float*)d_in[10];
    const float* P       = (const float*)d_in[11];
    const float* bg      = (const float*)d_in[12];

    float* out = (float*)d_out;
    float* ws  = (float*)d_ws;

    hipLaunchKernelGGL(k_pre, dim3(8), dim3(256), 0, stream,
                       means3D, colors, lang, opac, opacl, scales, scalesl,
                       rots, rotsl, V, P, ws, out);
    hipLaunchKernelGGL(k_render, dim3(256, 2), dim3(64 * NWAVE), 0, stream,
                       ws, bg, out);
}